// Round 4
// baseline (1132.010 us; speedup 1.0000x reference)
//
#include <hip/hip_runtime.h>
#include <hip/hip_fp16.h>

typedef _Float16 half_t;
typedef _Float16 half8 __attribute__((ext_vector_type(8)));
typedef float floatx4 __attribute__((ext_vector_type(4)));

// ---- sizes ----
#define T_STEPS 300
#define NMB     1024                 // N*M batch
#define XT_ROWS (T_STEPS*NMB + 16)   // +16 pad so A-fragment row reads never fault

// ws layout (bytes)
#define XT_OFF   0ULL
#define XT_BYTES ((unsigned long long)XT_ROWS*64*2)
#define WCH_OFF  (XT_OFF + XT_BYTES)          // wcomb as f16 [512][64]
#define WCH_BYTES (512ULL*64*2)
#define BC_OFF   (WCH_OFF + WCH_BYTES)        // biasc f32 [512]

// L_hat = -D^-1/2 A D^-1/2 for the hardcoded 15-node skeleton (row=dst, col=src)
#define S2 0.70710678118654752f
#define QH 0.5f
#define UU 0.40824829046386302f
#define TH 0.33333333333333333f
__constant__ float LHAT[225] = {
  0,0,-S2,0,0,0,0,0,0,0,0,0,0,0,0,
  0,0,0,-S2,0,0,0,0,0,0,0,0,0,0,0,
  -S2,0,0,0,-QH,0,0,0,0,0,0,0,0,0,0,
  0,-S2,0,0,0,-QH,0,0,0,0,0,0,0,0,0,
  0,0,-QH,0,0,0,0,0,0,0,0,0,0,0,-UU,
  0,0,0,-QH,0,0,0,0,0,0,0,0,0,0,-UU,
  0,0,0,0,0,0,0,0,-S2,0,0,0,0,0,0,
  0,0,0,0,0,0,0,0,0,-S2,0,0,0,0,0,
  0,0,0,0,0,0,-S2,0,0,0,-QH,0,0,0,0,
  0,0,0,0,0,0,0,-S2,0,0,0,-QH,0,0,0,
  0,0,0,0,0,0,0,0,-QH,0,0,0,0,-UU,0,
  0,0,0,0,0,0,0,0,0,-QH,0,0,0,-UU,0,
  0,0,0,0,0,0,0,0,0,0,0,0,0,0,0,
  0,0,0,0,0,0,0,0,0,0,-UU,-UU,0,0,0,
  0,0,0,0,-UU,-UU,0,0,0,0,0,0,0,-TH,0
};

// Fast gate math: v_exp_f32 + v_rcp_f32 (approx, ~1 ulp).
__device__ __forceinline__ float frcp(float x)  { return __builtin_amdgcn_rcpf(x); }
__device__ __forceinline__ float fsig(float x)  { return frcp(1.f + __expf(-x)); }
__device__ __forceinline__ float ftanh(float x) { return 2.f*frcp(1.f + __expf(-2.f*x)) - 1.f; }

__device__ __forceinline__ half8 load_w8(const float* p) {
  const float4* q = (const float4*)p;
  float4 a = q[0], b = q[1];
  half8 f;
  f[0]=(half_t)a.x; f[1]=(half_t)a.y; f[2]=(half_t)a.z; f[3]=(half_t)a.w;
  f[4]=(half_t)b.x; f[5]=(half_t)b.y; f[6]=(half_t)b.z; f[7]=(half_t)b.w;
  return f;
}

// Redistribute C-fragment rows 0..3 (held in quad-0 lanes' regs) so that
// lane (quad q, l16) gets reg q's value from quad-0 lane l16.
__device__ __forceinline__ float bperm_f(int addr, float v) {
  return __int_as_float(__builtin_amdgcn_ds_bpermute(addr, __float_as_int(v)));
}
__device__ __forceinline__ float sel_quad(const floatx4 a, int addr, int quad) {
  float t0 = bperm_f(addr, a[0]);
  float t1 = bperm_f(addr, a[1]);
  float t2 = bperm_f(addr, a[2]);
  float t3 = bperm_f(addr, a[3]);
  float a01 = (quad & 1) ? t1 : t0;
  float a23 = (quad & 1) ? t3 : t2;
  return (quad & 2) ? a23 : a01;
}

// ---- K0: fold ChebConv into layer-0 input projection: wcomb_h f16[512][64], biasc[512]
__global__ void k_prep(const float* __restrict__ w0, const float* __restrict__ w1,
                       const float* __restrict__ cb, const float* __restrict__ wih0,
                       const float* __restrict__ bih0, const float* __restrict__ bhh0,
                       half_t* __restrict__ wcomb_h, float* __restrict__ biasc) {
  const int n = threadIdx.x; // 512 threads, 1 block
  float wrow[45];
  #pragma unroll
  for (int i=0;i<45;i++) wrow[i] = wih0[n*45+i];
  float P[45];
  #pragma unroll
  for (int i=0;i<15;i++)
    #pragma unroll
    for (int c=0;c<3;c++) {
      float s = 0.f;
      #pragma unroll
      for (int cp=0;cp<3;cp++) s += wrow[i*3+cp]*w1[cp*3+c];
      P[i*3+c] = s;
    }
  #pragma unroll
  for (int j=0;j<15;j++)
    #pragma unroll
    for (int c=0;c<3;c++) {
      float s = 0.f;
      #pragma unroll
      for (int cp=0;cp<3;cp++) s += wrow[j*3+cp]*w0[cp*3+c];
      #pragma unroll
      for (int i=0;i<15;i++) s += LHAT[i*15+j]*P[i*3+c];
      wcomb_h[n*64 + j*3+c] = (half_t)s;
    }
  for (int k=45;k<64;k++) wcomb_h[n*64+k] = (half_t)0.f;
  float b = bih0[n] + bhh0[n];
  #pragma unroll
  for (int i=0;i<15;i++)
    #pragma unroll
    for (int cp=0;cp<3;cp++) b += wrow[i*3+cp]*cb[cp];
  biasc[n] = b;
}

// ---- K0b: x1 [N,C,T,V,M] fp32 -> xt [t*1024+nm][64] fp16 (features v*3+c, 45 valid)
__global__ void k_xpose(const float* __restrict__ x1, half_t* __restrict__ xt) {
  const int id = blockIdx.x*256 + threadIdx.x;   // exactly 512*3*300*15 = 6,912,000
  const int v  = id % 15;
  const int r1 = id / 15;
  const int t  = r1 % 300;
  const int r2 = r1 / 300;
  const int c  = r2 % 3;
  const int n  = r2 / 3;
  const float2 f = ((const float2*)x1)[id];      // m=0,1 pair, coalesced
  const size_t row = (size_t)t*NMB + n*2;
  xt[row*64     + v*3 + c] = (half_t)f.x;
  xt[(row+1)*64 + v*3 + c] = (half_t)f.y;
}

// ---- Fused 2-layer LSTM + FC + softmax. 256 WGs x 512 threads; 4 batch rows/WG.
// Layer-1 runs one step behind layer-0 (reads h0[t-1]); single barrier per step.
// Layer-0 input projection computed in 8-step blocks (phase A) into wave-private
// LDS stash; recurrent phase B adds it pre-nonlinearity.
__launch_bounds__(512, 2)
__global__ void k_fused(const half_t* __restrict__ xt, const half_t* __restrict__ wch,
                        const float* __restrict__ biasc, const float* __restrict__ whh0,
                        const float* __restrict__ wih1, const float* __restrict__ whh1,
                        const float* __restrict__ bih1, const float* __restrict__ bhh1,
                        const float* __restrict__ fcw, const float* __restrict__ fcb,
                        float* __restrict__ out) {
  __shared__ __align__(16) half_t h0b[2][16*136];
  __shared__ __align__(16) half_t h1b[2][16*136];
  __shared__ __align__(16) float  gxs[8*2048];   // 8 waves x (8 steps x 4nt x 16 lanes x 4)
  __shared__ float logits_lds[240];
  const int tid = threadIdx.x;
  const int wave = tid>>6, lane = tid&63, quad = lane>>4, l16 = lane&15;
  const int nm0 = blockIdx.x*4;
  const int addr16 = l16<<2;                      // bpermute source-lane byte addr
  for (int i=tid; i<2*16*136; i+=512) { h0b[0][i] = (half_t)0.f; h1b[0][i] = (half_t)0.f; }

  // Resident weight B-frags: B[k][n] = W[gcol][k]; gcol = gate*128 + wave*16 + l16
  half8 whh0F[4][4], wih1F[4][4], whh1F[4][4];
  float bias0[4], bias1[4];
  #pragma unroll
  for (int nt=0; nt<4; nt++) {
    const int gcol = nt*128 + wave*16 + l16;
    #pragma unroll
    for (int kc=0; kc<4; kc++) {
      whh0F[nt][kc] = load_w8(whh0 + gcol*128 + kc*32 + quad*8);
      wih1F[nt][kc] = load_w8(wih1 + gcol*128 + kc*32 + quad*8);
      whh1F[nt][kc] = load_w8(whh1 + gcol*128 + kc*32 + quad*8);
    }
    bias0[nt] = biasc[gcol];
    bias1[nt] = bih1[gcol] + bhh1[gcol];
  }
  float cst0 = 0.f, cst1 = 0.f;   // per-lane cell state: (row=quad, col=wave*16+l16)
  float* gxw = gxs + wave*2048;
  __syncthreads();

  for (int bs = 0; bs < T_STEPS; bs += 8) {
    const int cnt = (T_STEPS - bs < 8) ? (T_STEPS - bs) : 8;
    // ---- phase A: input projection for steps bs..bs+cnt-1 (no barrier needed)
    {
      const half_t* xp = xt + ((size_t)bs*NMB + nm0 + l16)*64 + quad*8;
      for (int s = 0; s < cnt; s++) {
        half8 xv0 = *(const half8*)(xp);
        half8 xv1 = *(const half8*)(xp + 32);
        xp += (size_t)NMB*64;
        #pragma unroll
        for (int nt=0; nt<4; nt++) {
          const int gcol = nt*128 + wave*16 + l16;
          half8 w0f = *(const half8*)(wch + gcol*64 +      quad*8);
          half8 w1f = *(const half8*)(wch + gcol*64 + 32 + quad*8);
          floatx4 a = {0.f,0.f,0.f,0.f};
          a = __builtin_amdgcn_mfma_f32_16x16x32_f16(xv0, w0f, a, 0,0,0);
          a = __builtin_amdgcn_mfma_f32_16x16x32_f16(xv1, w1f, a, 0,0,0);
          if (quad == 0) *(floatx4*)(gxw + ((s*4+nt)*16 + l16)*4) = a;
        }
      }
    }
    // ---- phase B: recurrent steps
    for (int s = 0; s < cnt; s++) {
      const int t = bs + s;
      const half_t* h0r = &h0b[t&1][0];
      const half_t* h1r = &h1b[t&1][0];

      // layer 0: gates = h0[t-1] @ Whh0^T + gx[t]
      floatx4 acc[4];
      #pragma unroll
      for (int nt=0; nt<4; nt++) { floatx4 z = {0.f,0.f,0.f,0.f}; acc[nt] = z; }
      #pragma unroll
      for (int kc=0; kc<4; kc++) {
        half8 hA = *(const half8*)(h0r + l16*136 + kc*32 + quad*8);
        #pragma unroll
        for (int nt=0; nt<4; nt++)
          acc[nt] = __builtin_amdgcn_mfma_f32_16x16x32_f16(hA, whh0F[nt][kc], acc[nt], 0,0,0);
      }
      #pragma unroll
      for (int nt=0; nt<4; nt++) {   // unguarded: only quad-0 values matter downstream
        floatx4 g = *(const floatx4*)(gxw + ((s*4+nt)*16 + l16)*4);
        acc[nt] += g;
      }
      float g0[4];
      #pragma unroll
      for (int nt=0; nt<4; nt++) g0[nt] = sel_quad(acc[nt], addr16, quad);
      cst0 = fsig(g0[1]+bias0[1])*cst0 + fsig(g0[0]+bias0[0])*ftanh(g0[2]+bias0[2]);
      const half_t h0v = (half_t)(fsig(g0[3]+bias0[3])*ftanh(cst0));

      // layer 1 (computes step t-1): gates = h0[t-1] @ Wih1^T + h1[t-2] @ Whh1^T
      #pragma unroll
      for (int nt=0; nt<4; nt++) { floatx4 z = {0.f,0.f,0.f,0.f}; acc[nt] = z; }
      #pragma unroll
      for (int kc=0; kc<4; kc++) {
        half8 hA = *(const half8*)(h0r + l16*136 + kc*32 + quad*8);
        #pragma unroll
        for (int nt=0; nt<4; nt++)
          acc[nt] = __builtin_amdgcn_mfma_f32_16x16x32_f16(hA, wih1F[nt][kc], acc[nt], 0,0,0);
      }
      #pragma unroll
      for (int kc=0; kc<4; kc++) {
        half8 hB = *(const half8*)(h1r + l16*136 + kc*32 + quad*8);
        #pragma unroll
        for (int nt=0; nt<4; nt++)
          acc[nt] = __builtin_amdgcn_mfma_f32_16x16x32_f16(hB, whh1F[nt][kc], acc[nt], 0,0,0);
      }
      float g1[4];
      #pragma unroll
      for (int nt=0; nt<4; nt++) g1[nt] = sel_quad(acc[nt], addr16, quad);
      if (t > 0) {   // at t==0 layer-1 has no input yet; keep cst1=0, h1b[1] stays 0
        cst1 = fsig(g1[1]+bias1[1])*cst1 + fsig(g1[0]+bias1[0])*ftanh(g1[2]+bias1[2]);
        h1b[(t+1)&1][quad*136 + wave*16 + l16] = (half_t)(fsig(g1[3]+bias1[3])*ftanh(cst1));
      }
      h0b[(t+1)&1][quad*136 + wave*16 + l16] = h0v;
      __syncthreads();
    }
  }

  // ---- peeled final layer-1 step (t=299): reads h0[299]=h0b[0], h1[298]=h1b[0]
  {
    floatx4 acc[4];
    #pragma unroll
    for (int nt=0; nt<4; nt++) { floatx4 z = {0.f,0.f,0.f,0.f}; acc[nt] = z; }
    #pragma unroll
    for (int kc=0; kc<4; kc++) {
      half8 hA = *(const half8*)(&h0b[0][0] + l16*136 + kc*32 + quad*8);
      #pragma unroll
      for (int nt=0; nt<4; nt++)
        acc[nt] = __builtin_amdgcn_mfma_f32_16x16x32_f16(hA, wih1F[nt][kc], acc[nt], 0,0,0);
    }
    #pragma unroll
    for (int kc=0; kc<4; kc++) {
      half8 hB = *(const half8*)(&h1b[0][0] + l16*136 + kc*32 + quad*8);
      #pragma unroll
      for (int nt=0; nt<4; nt++)
        acc[nt] = __builtin_amdgcn_mfma_f32_16x16x32_f16(hB, whh1F[nt][kc], acc[nt], 0,0,0);
    }
    float g1[4];
    #pragma unroll
    for (int nt=0; nt<4; nt++) g1[nt] = sel_quad(acc[nt], addr16, quad);
    cst1 = fsig(g1[1]+bias1[1])*cst1 + fsig(g1[0]+bias1[0])*ftanh(g1[2]+bias1[2]);
    h1b[1][quad*136 + wave*16 + l16] = (half_t)(fsig(g1[3]+bias1[3])*ftanh(cst1));
  }
  __syncthreads();

  // ---- FC (60 classes) + softmax; h1[299] in h1b[1] rows 0..3
  if (tid < 240) {
    const int r2 = tid/60, cls = tid%60;
    float s = fcb[cls];
    for (int k2=0; k2<128; k2++) s += (float)h1b[1][r2*136+k2] * fcw[cls*128+k2];
    logits_lds[r2*60+cls] = s;
  }
  __syncthreads();
  if (tid < 4) {
    float m = -1e30f;
    for (int j=0; j<60; j++) m = fmaxf(m, logits_lds[tid*60+j]);
    float s = 0.f;
    for (int j=0; j<60; j++) s += __expf(logits_lds[tid*60+j]-m);
    const float inv = frcp(s);
    for (int j=0; j<60; j++) out[(nm0+tid)*60+j] = __expf(logits_lds[tid*60+j]-m)*inv;
  }
}

extern "C" void kernel_launch(void* const* d_in, const int* in_sizes, int n_in,
                              void* d_out, int out_size, void* d_ws, size_t ws_size,
                              hipStream_t stream) {
  const float* x1      = (const float*)d_in[0];
  const float* cheb_w0 = (const float*)d_in[2];
  const float* cheb_w1 = (const float*)d_in[3];
  const float* cheb_b  = (const float*)d_in[4];
  const float* wih0    = (const float*)d_in[5];
  const float* whh0    = (const float*)d_in[6];
  const float* bih0    = (const float*)d_in[7];
  const float* bhh0    = (const float*)d_in[8];
  const float* wih1    = (const float*)d_in[9];
  const float* whh1    = (const float*)d_in[10];
  const float* bih1    = (const float*)d_in[11];
  const float* bhh1    = (const float*)d_in[12];
  const float* fc_w    = (const float*)d_in[13];
  const float* fc_b    = (const float*)d_in[14];

  char* ws = (char*)d_ws;
  half_t* xt    = (half_t*)(ws + XT_OFF);
  half_t* wch   = (half_t*)(ws + WCH_OFF);
  float*  biasc = (float*)(ws + BC_OFF);

  k_prep <<<dim3(1),     dim3(512), 0, stream>>>(cheb_w0, cheb_w1, cheb_b, wih0, bih0, bhh0, wch, biasc);
  k_xpose<<<dim3(27000), dim3(256), 0, stream>>>(x1, xt);
  k_fused<<<dim3(256),   dim3(512), 0, stream>>>(xt, wch, biasc, whh0, wih1, whh1,
                                                 bih1, bhh1, fc_w, fc_b, (float*)d_out);
}